// Round 1
// baseline (851.890 us; speedup 1.0000x reference)
//
#include <hip/hip_runtime.h>
#include <math.h>

// Problem constants (from reference: h,w,d = 51^3 nodes, avg degree 64)
constexpr int N_NODES = 51 * 51 * 51;        // 132651
constexpr int N_EDGES = N_NODES * 64;        // 8489664
constexpr int E_HALF  = N_EDGES / 2;         // 4244832
constexpr int NP      = (N_NODES + 255) & ~255;  // 132864, padded for ws layout

// ---------------- kernels ----------------

__global__ __launch_bounds__(256) void k_init_deg(int* __restrict__ deg) {
    int i = blockIdx.x * 256 + threadIdx.x;
    if (i < N_NODES) deg[i] = 1;  // self-loop counted
}

// deg[v] += #edges with col==v  (int atomics; col read is the only big traffic)
__global__ __launch_bounds__(256) void k_deg(const int4* __restrict__ col4,
                                             int* __restrict__ deg) {
    int i = blockIdx.x * 256 + threadIdx.x;
    const int stride = gridDim.x * 256;
    const int n4 = N_EDGES / 4;
    for (; i < n4; i += stride) {
        int4 c = col4[i];
        atomicAdd(&deg[c.x], 1);
        atomicAdd(&deg[c.y], 1);
        atomicAdd(&deg[c.z], 1);
        atomicAdd(&deg[c.w], 1);
    }
}

// dinv[v] = rsqrt(deg[v]);  t[v] initialized with self-loop term dinv^2 * x[v]
__global__ __launch_bounds__(256) void k_dinv(const int* __restrict__ deg,
                                              const float* __restrict__ x,
                                              float* __restrict__ dinv,
                                              float* __restrict__ t) {
    int i = blockIdx.x * 256 + threadIdx.x;
    if (i >= N_NODES) return;
    float d = rsqrtf((float)deg[i]);   // deg >= 1 always (self-loop)
    dinv[i] = d;
    t[i] = d * d * x[i];
}

// t[col] += dinv[row]*dinv[col]*x[row]  — one float atomic per edge
__global__ __launch_bounds__(256) void k_scatter(const int4* __restrict__ row4,
                                                 const int4* __restrict__ col4,
                                                 const float* __restrict__ x,
                                                 const float* __restrict__ dinv,
                                                 float* __restrict__ t) {
    int i = blockIdx.x * 256 + threadIdx.x;
    const int stride = gridDim.x * 256;
    const int n4 = N_EDGES / 4;
    for (; i < n4; i += stride) {
        int4 r = row4[i];
        int4 c = col4[i];
        atomicAdd(&t[c.x], dinv[r.x] * dinv[c.x] * x[r.x]);
        atomicAdd(&t[c.y], dinv[r.y] * dinv[c.y] * x[r.y]);
        atomicAdd(&t[c.z], dinv[r.z] * dinv[c.z] * x[r.z]);
        atomicAdd(&t[c.w], dinv[r.w] * dinv[c.w] * x[r.w]);
    }
}

// s[v] = relu(t*W0+b0) + relu(t*W1+b1)
__global__ __launch_bounds__(256) void k_node(const float* __restrict__ t,
                                              const float* __restrict__ W,
                                              const float* __restrict__ b,
                                              float* __restrict__ s) {
    int i = blockIdx.x * 256 + threadIdx.x;
    if (i >= N_NODES) return;
    float tv = t[i];
    float h0 = fmaxf(fmaf(tv, W[0], b[0]), 0.f);
    float h1 = fmaxf(fmaf(tv, W[1], b[1]), 0.f);
    s[i] = h0 + h1;
}

// out[i] = sigmoid(0.5*(s[row_i]+s[col_i]+s[row_{i+EH}]+s[col_{i+EH}]))
__global__ __launch_bounds__(256) void k_out(const int4* __restrict__ rowA,
                                             const int4* __restrict__ colA,
                                             const int4* __restrict__ rowB,
                                             const int4* __restrict__ colB,
                                             const float* __restrict__ s,
                                             float4* __restrict__ out) {
    int i = blockIdx.x * 256 + threadIdx.x;
    const int stride = gridDim.x * 256;
    const int n4 = E_HALF / 4;
    for (; i < n4; i += stride) {
        int4 ra = rowA[i], ca = colA[i], rb = rowB[i], cb = colB[i];
        float y0 = s[ra.x] + s[ca.x] + s[rb.x] + s[cb.x];
        float y1 = s[ra.y] + s[ca.y] + s[rb.y] + s[cb.y];
        float y2 = s[ra.z] + s[ca.z] + s[rb.z] + s[cb.z];
        float y3 = s[ra.w] + s[ca.w] + s[rb.w] + s[cb.w];
        float4 o;
        o.x = 1.f / (1.f + __expf(-0.5f * y0));
        o.y = 1.f / (1.f + __expf(-0.5f * y1));
        o.z = 1.f / (1.f + __expf(-0.5f * y2));
        o.w = 1.f / (1.f + __expf(-0.5f * y3));
        out[i] = o;
    }
}

// ---------------- launch ----------------

extern "C" void kernel_launch(void* const* d_in, const int* in_sizes, int n_in,
                              void* d_out, int out_size, void* d_ws, size_t ws_size,
                              hipStream_t stream) {
    const float* x = (const float*)d_in[0];    // [N,1]
    const float* W = (const float*)d_in[1];    // [1,2]
    const float* b = (const float*)d_in[2];    // [2]
    const int*   ei = (const int*)d_in[3];     // [2,E] int32 on device
    const int* row = ei;
    const int* col = ei + N_EDGES;
    float* out = (float*)d_out;                // [E/2] float32

    // workspace layout (all fully re-initialized every call; ws is NOT
    // re-poisoned between replays, so nothing may be carried over)
    char* ws = (char*)d_ws;
    int*   deg  = (int*)(ws);                  // NP ints
    float* dinv = (float*)(ws + (size_t)NP * 4);
    float* t    = (float*)(ws + (size_t)NP * 8);
    float* s    = (float*)(ws + (size_t)NP * 12);

    const int nodeBlocks = (N_NODES + 255) / 256;  // 519
    const int edgeBlocks = 2048;                   // grid-stride caps

    k_init_deg<<<nodeBlocks, 256, 0, stream>>>(deg);
    k_deg<<<edgeBlocks, 256, 0, stream>>>((const int4*)col, deg);
    k_dinv<<<nodeBlocks, 256, 0, stream>>>(deg, x, dinv, t);
    k_scatter<<<edgeBlocks, 256, 0, stream>>>((const int4*)row, (const int4*)col,
                                              x, dinv, t);
    k_node<<<nodeBlocks, 256, 0, stream>>>(t, W, b, s);
    k_out<<<edgeBlocks, 256, 0, stream>>>((const int4*)row, (const int4*)col,
                                          (const int4*)(row + E_HALF),
                                          (const int4*)(col + E_HALF),
                                          s, (float4*)out);
}

// Round 2
// 244.778 us; speedup vs baseline: 3.4803x; 3.4803x over previous
//
#include <hip/hip_runtime.h>
#include <math.h>

// Problem constants (from reference: 51^3 nodes, avg degree 64)
constexpr int N_NODES = 51 * 51 * 51;        // 132651
constexpr int N_EDGES = N_NODES * 64;        // 8489664
constexpr int E_HALF  = N_EDGES / 2;         // 4244832
constexpr int NP      = (N_NODES + 255) & ~255;  // padded node count

constexpr int PART   = 16384;                // nodes per partition (64 KB LDS)
constexpr int PSHIFT = 14;
constexpr int NPARTS = (N_NODES + PART - 1) / PART;  // 9
constexpr int BP_MAX = 56;                   // blocks per partition (504 total)

// ================= partitioned-LDS path (no global atomics) =================

// Pass A: degree histogram. Block (p,b): LDS counts for node range
// [p*PART, p*PART+PART); streams slice b of col[], flushes to partial[].
__global__ __launch_bounds__(512) void k_deg_part(const int4* __restrict__ col4,
                                                  unsigned* __restrict__ partial,
                                                  int Bp) {
    __shared__ unsigned cnt[PART];
    const int p = blockIdx.x / Bp;
    const int b = blockIdx.x % Bp;
    const int base = p * PART;
    for (int j = threadIdx.x; j < PART; j += blockDim.x) cnt[j] = 0;
    __syncthreads();
    const int n4 = N_EDGES / 4;
    const int stride = Bp * blockDim.x;
    for (int i = b * blockDim.x + threadIdx.x; i < n4; i += stride) {
        int4 c = col4[i];
        unsigned j;
        j = (unsigned)(c.x - base); if (j < (unsigned)PART) atomicAdd(&cnt[j], 1u);
        j = (unsigned)(c.y - base); if (j < (unsigned)PART) atomicAdd(&cnt[j], 1u);
        j = (unsigned)(c.z - base); if (j < (unsigned)PART) atomicAdd(&cnt[j], 1u);
        j = (unsigned)(c.w - base); if (j < (unsigned)PART) atomicAdd(&cnt[j], 1u);
    }
    __syncthreads();
    unsigned* dst = partial + (size_t)blockIdx.x * PART;
    for (int j = threadIdx.x; j < PART; j += blockDim.x) dst[j] = cnt[j];
}

// Reduce A: deg[v] = 1 + sum_b partial;  dinv = rsqrt(deg);  u = dinv * x.
__global__ __launch_bounds__(256) void k_reduceA(const unsigned* __restrict__ partial,
                                                 const float* __restrict__ x,
                                                 int Bp,
                                                 float* __restrict__ dinv,
                                                 float* __restrict__ u) {
    int v = blockIdx.x * 256 + threadIdx.x;
    if (v >= N_NODES) return;
    const int p = v >> PSHIFT;
    const int j = v & (PART - 1);
    const unsigned* src = partial + (size_t)(p * Bp) * PART + j;
    unsigned deg = 1;  // self-loop
    for (int b = 0; b < Bp; ++b) deg += src[(size_t)b * PART];
    float d = rsqrtf((float)deg);
    dinv[v] = d;
    u[v] = d * x[v];
}

// Pass B: weighted scatter g[col] += u[row] via LDS float atomics.
__global__ __launch_bounds__(512) void k_scat_part(const int4* __restrict__ row4,
                                                   const int4* __restrict__ col4,
                                                   const float* __restrict__ u,
                                                   float* __restrict__ partial,
                                                   int Bp) {
    __shared__ float acc[PART];
    const int p = blockIdx.x / Bp;
    const int b = blockIdx.x % Bp;
    const int base = p * PART;
    for (int j = threadIdx.x; j < PART; j += blockDim.x) acc[j] = 0.f;
    __syncthreads();
    const int n4 = N_EDGES / 4;
    const int stride = Bp * blockDim.x;
    for (int i = b * blockDim.x + threadIdx.x; i < n4; i += stride) {
        int4 c = col4[i];
        int4 r = row4[i];
        unsigned j;
        j = (unsigned)(c.x - base); if (j < (unsigned)PART) atomicAdd(&acc[j], u[r.x]);
        j = (unsigned)(c.y - base); if (j < (unsigned)PART) atomicAdd(&acc[j], u[r.y]);
        j = (unsigned)(c.z - base); if (j < (unsigned)PART) atomicAdd(&acc[j], u[r.z]);
        j = (unsigned)(c.w - base); if (j < (unsigned)PART) atomicAdd(&acc[j], u[r.w]);
    }
    __syncthreads();
    float* dst = partial + (size_t)blockIdx.x * PART;
    for (int j = threadIdx.x; j < PART; j += blockDim.x) dst[j] = acc[j];
}

// Reduce B: t = dinv*(g+u);  s = relu(t*W0+b0) + relu(t*W1+b1).
__global__ __launch_bounds__(256) void k_reduceB(const float* __restrict__ partial,
                                                 const float* __restrict__ dinv,
                                                 const float* __restrict__ u,
                                                 const float* __restrict__ W,
                                                 const float* __restrict__ bb,
                                                 int Bp,
                                                 float* __restrict__ s) {
    int v = blockIdx.x * 256 + threadIdx.x;
    if (v >= N_NODES) return;
    const int p = v >> PSHIFT;
    const int j = v & (PART - 1);
    const float* src = partial + (size_t)(p * Bp) * PART + j;
    float g = 0.f;
    for (int b = 0; b < Bp; ++b) g += src[(size_t)b * PART];
    float t = dinv[v] * (g + u[v]);
    float h0 = fmaxf(fmaf(t, W[0], bb[0]), 0.f);
    float h1 = fmaxf(fmaf(t, W[1], bb[1]), 0.f);
    s[v] = h0 + h1;
}

// ================= fallback path (global atomics, proven) =================

__global__ __launch_bounds__(256) void k_init_deg(int* __restrict__ deg) {
    int i = blockIdx.x * 256 + threadIdx.x;
    if (i < N_NODES) deg[i] = 1;
}

__global__ __launch_bounds__(256) void k_deg(const int4* __restrict__ col4,
                                             int* __restrict__ deg) {
    int i = blockIdx.x * 256 + threadIdx.x;
    const int stride = gridDim.x * 256;
    const int n4 = N_EDGES / 4;
    for (; i < n4; i += stride) {
        int4 c = col4[i];
        atomicAdd(&deg[c.x], 1); atomicAdd(&deg[c.y], 1);
        atomicAdd(&deg[c.z], 1); atomicAdd(&deg[c.w], 1);
    }
}

__global__ __launch_bounds__(256) void k_dinv(const int* __restrict__ deg,
                                              const float* __restrict__ x,
                                              float* __restrict__ dinv,
                                              float* __restrict__ t) {
    int i = blockIdx.x * 256 + threadIdx.x;
    if (i >= N_NODES) return;
    float d = rsqrtf((float)deg[i]);
    dinv[i] = d;
    t[i] = d * d * x[i];
}

__global__ __launch_bounds__(256) void k_scatter(const int4* __restrict__ row4,
                                                 const int4* __restrict__ col4,
                                                 const float* __restrict__ x,
                                                 const float* __restrict__ dinv,
                                                 float* __restrict__ t) {
    int i = blockIdx.x * 256 + threadIdx.x;
    const int stride = gridDim.x * 256;
    const int n4 = N_EDGES / 4;
    for (; i < n4; i += stride) {
        int4 r = row4[i];
        int4 c = col4[i];
        atomicAdd(&t[c.x], dinv[r.x] * dinv[c.x] * x[r.x]);
        atomicAdd(&t[c.y], dinv[r.y] * dinv[c.y] * x[r.y]);
        atomicAdd(&t[c.z], dinv[r.z] * dinv[c.z] * x[r.z]);
        atomicAdd(&t[c.w], dinv[r.w] * dinv[c.w] * x[r.w]);
    }
}

__global__ __launch_bounds__(256) void k_node(const float* __restrict__ t,
                                              const float* __restrict__ W,
                                              const float* __restrict__ b,
                                              float* __restrict__ s) {
    int i = blockIdx.x * 256 + threadIdx.x;
    if (i >= N_NODES) return;
    float tv = t[i];
    float h0 = fmaxf(fmaf(tv, W[0], b[0]), 0.f);
    float h1 = fmaxf(fmaf(tv, W[1], b[1]), 0.f);
    s[i] = h0 + h1;
}

// ================= shared output kernel =================

__global__ __launch_bounds__(256) void k_out(const int4* __restrict__ rowA,
                                             const int4* __restrict__ colA,
                                             const int4* __restrict__ rowB,
                                             const int4* __restrict__ colB,
                                             const float* __restrict__ s,
                                             float4* __restrict__ out) {
    int i = blockIdx.x * 256 + threadIdx.x;
    const int stride = gridDim.x * 256;
    const int n4 = E_HALF / 4;
    for (; i < n4; i += stride) {
        int4 ra = rowA[i], ca = colA[i], rb = rowB[i], cb = colB[i];
        float y0 = s[ra.x] + s[ca.x] + s[rb.x] + s[cb.x];
        float y1 = s[ra.y] + s[ca.y] + s[rb.y] + s[cb.y];
        float y2 = s[ra.z] + s[ca.z] + s[rb.z] + s[cb.z];
        float y3 = s[ra.w] + s[ca.w] + s[rb.w] + s[cb.w];
        float4 o;
        o.x = 1.f / (1.f + __expf(-0.5f * y0));
        o.y = 1.f / (1.f + __expf(-0.5f * y1));
        o.z = 1.f / (1.f + __expf(-0.5f * y2));
        o.w = 1.f / (1.f + __expf(-0.5f * y3));
        out[i] = o;
    }
}

// ================= launch =================

extern "C" void kernel_launch(void* const* d_in, const int* in_sizes, int n_in,
                              void* d_out, int out_size, void* d_ws, size_t ws_size,
                              hipStream_t stream) {
    const float* x = (const float*)d_in[0];
    const float* W = (const float*)d_in[1];
    const float* b = (const float*)d_in[2];
    const int*   ei = (const int*)d_in[3];
    const int* row = ei;
    const int* col = ei + N_EDGES;
    float* out = (float*)d_out;

    char* ws = (char*)d_ws;
    // node arrays (both paths)
    float* dinv = (float*)(ws);                         // NP floats
    float* u    = (float*)(ws + (size_t)NP * 4);        // NP floats (aka t in fallback)
    float* s    = (float*)(ws + (size_t)NP * 8);        // NP floats
    int*   deg  = (int*)  (ws + (size_t)NP * 12);       // NP ints (fallback only)
    char*  partialBase = ws + (size_t)NP * 16;
    size_t avail = (ws_size > (size_t)NP * 16) ? ws_size - (size_t)NP * 16 : 0;

    // pick blocks-per-partition from available workspace
    int Bp = (int)(avail / ((size_t)PART * 4 * NPARTS));
    if (Bp > BP_MAX) Bp = BP_MAX;

    const int nodeBlocks = (N_NODES + 255) / 256;
    const int edgeBlocks = 2048;

    if (Bp >= 4) {
        unsigned* partU = (unsigned*)partialBase;
        float*    partF = (float*)partialBase;  // reused sequentially
        const int TB = NPARTS * Bp;
        k_deg_part<<<TB, 512, 0, stream>>>((const int4*)col, partU, Bp);
        k_reduceA<<<nodeBlocks, 256, 0, stream>>>(partU, x, Bp, dinv, u);
        k_scat_part<<<TB, 512, 0, stream>>>((const int4*)row, (const int4*)col,
                                            u, partF, Bp);
        k_reduceB<<<nodeBlocks, 256, 0, stream>>>(partF, dinv, u, W, b, Bp, s);
    } else {
        // fallback: global-atomic path
        k_init_deg<<<nodeBlocks, 256, 0, stream>>>(deg);
        k_deg<<<edgeBlocks, 256, 0, stream>>>((const int4*)col, deg);
        k_dinv<<<nodeBlocks, 256, 0, stream>>>(deg, x, dinv, u);
        k_scatter<<<edgeBlocks, 256, 0, stream>>>((const int4*)row, (const int4*)col,
                                                  x, dinv, u);
        k_node<<<nodeBlocks, 256, 0, stream>>>(u, W, b, s);
    }

    k_out<<<edgeBlocks, 256, 0, stream>>>((const int4*)row, (const int4*)col,
                                          (const int4*)(row + E_HALF),
                                          (const int4*)(col + E_HALF),
                                          s, (float4*)out);
}

// Round 3
// 193.057 us; speedup vs baseline: 4.4126x; 1.2679x over previous
//
#include <hip/hip_runtime.h>
#include <math.h>

// Problem constants (from reference: 51^3 nodes, avg degree 64)
constexpr int N_NODES = 51 * 51 * 51;        // 132651
constexpr int N_EDGES = N_NODES * 64;        // 8489664
constexpr int E_HALF  = N_EDGES / 2;         // 4244832
constexpr int NP      = (N_NODES + 255) & ~255;  // padded node count

// Scatter partitioning: f32 accumulators, 144 KB LDS (gfx950 allows 160 KB/WG)
constexpr int PART_S = 36864;                 // 36864 * 4 B = 147456 B LDS
constexpr int NP_S   = 4;                     // 4 * 36864 = 147456 >= N_NODES
// Degree partitioning: packed u16 counters, 2 per u32 word, same 144 KB LDS
constexpr int PART_D  = 73728;                // u16 counters
constexpr int NP_D    = 2;                    // 2 * 73728 = 147456 >= N_NODES
constexpr int WORDS_D = PART_D / 2;           // 36864 u32 words

// ================= partitioned-LDS path (no global atomics) =================

// Pass A: degree histogram with packed u16 counters. Overflow impossible:
// each block scans ~8.5M/Bp edges; max hits per node per block << 65536.
__global__ __launch_bounds__(1024) void k_deg_part(const int4* __restrict__ col4,
                                                   unsigned* __restrict__ partial,
                                                   int Bp) {
    __shared__ unsigned cnt[WORDS_D];
    const int p = blockIdx.x / Bp;
    const int b = blockIdx.x % Bp;
    const int base = p * PART_D;
    for (int j = threadIdx.x; j < WORDS_D; j += 1024) cnt[j] = 0u;
    __syncthreads();
    const int n4 = N_EDGES / 4;
    const int stride = Bp * 1024;
    for (int i = b * 1024 + threadIdx.x; i < n4; i += stride) {
        int4 c = col4[i];
        unsigned j;
        j = (unsigned)(c.x - base);
        if (j < (unsigned)PART_D) atomicAdd(&cnt[j >> 1], 1u << ((j & 1) << 4));
        j = (unsigned)(c.y - base);
        if (j < (unsigned)PART_D) atomicAdd(&cnt[j >> 1], 1u << ((j & 1) << 4));
        j = (unsigned)(c.z - base);
        if (j < (unsigned)PART_D) atomicAdd(&cnt[j >> 1], 1u << ((j & 1) << 4));
        j = (unsigned)(c.w - base);
        if (j < (unsigned)PART_D) atomicAdd(&cnt[j >> 1], 1u << ((j & 1) << 4));
    }
    __syncthreads();
    unsigned* dst = partial + (size_t)blockIdx.x * WORDS_D;
    for (int j = threadIdx.x; j < WORDS_D; j += 1024) dst[j] = cnt[j];
}

// Reduce A: deg[v] = 1 + sum_b cnt;  dinv = rsqrt(deg);  u = dinv * x.
__global__ __launch_bounds__(256) void k_reduceA(const unsigned* __restrict__ partial,
                                                 const float* __restrict__ x,
                                                 int Bp,
                                                 float* __restrict__ dinv,
                                                 float* __restrict__ u) {
    int v = blockIdx.x * 256 + threadIdx.x;
    if (v >= N_NODES) return;
    const int p = (v >= PART_D) ? 1 : 0;
    const int j = v - p * PART_D;
    const int word = j >> 1;
    const int sh = (j & 1) << 4;
    const unsigned* src = partial + (size_t)(p * Bp) * WORDS_D + word;
    unsigned deg = 1;  // self-loop
    for (int b = 0; b < Bp; ++b) deg += (src[(size_t)b * WORDS_D] >> sh) & 0xFFFFu;
    float d = rsqrtf((float)deg);
    dinv[v] = d;
    u[v] = d * x[v];
}

// Pass B: weighted scatter g[col] += u[row] via LDS float atomics.
__global__ __launch_bounds__(1024) void k_scat_part(const int4* __restrict__ row4,
                                                    const int4* __restrict__ col4,
                                                    const float* __restrict__ u,
                                                    float* __restrict__ partial,
                                                    int Bp) {
    __shared__ float acc[PART_S];
    const int p = blockIdx.x / Bp;
    const int b = blockIdx.x % Bp;
    const int base = p * PART_S;
    for (int j = threadIdx.x; j < PART_S; j += 1024) acc[j] = 0.f;
    __syncthreads();
    const int n4 = N_EDGES / 4;
    const int stride = Bp * 1024;
    for (int i = b * 1024 + threadIdx.x; i < n4; i += stride) {
        int4 c = col4[i];
        int4 r = row4[i];
        unsigned j;
        j = (unsigned)(c.x - base);
        if (j < (unsigned)PART_S) atomicAdd(&acc[j], u[r.x]);
        j = (unsigned)(c.y - base);
        if (j < (unsigned)PART_S) atomicAdd(&acc[j], u[r.y]);
        j = (unsigned)(c.z - base);
        if (j < (unsigned)PART_S) atomicAdd(&acc[j], u[r.z]);
        j = (unsigned)(c.w - base);
        if (j < (unsigned)PART_S) atomicAdd(&acc[j], u[r.w]);
    }
    __syncthreads();
    float* dst = partial + (size_t)blockIdx.x * PART_S;
    for (int j = threadIdx.x; j < PART_S; j += 1024) dst[j] = acc[j];
}

// Reduce B: t = dinv*(g+u);  s = relu(t*W0+b0) + relu(t*W1+b1).
__global__ __launch_bounds__(256) void k_reduceB(const float* __restrict__ partial,
                                                 const float* __restrict__ dinv,
                                                 const float* __restrict__ u,
                                                 const float* __restrict__ W,
                                                 const float* __restrict__ bb,
                                                 int Bp,
                                                 float* __restrict__ s) {
    int v = blockIdx.x * 256 + threadIdx.x;
    if (v >= N_NODES) return;
    const int p = (unsigned)v / (unsigned)PART_S;  // const-div -> magic mul
    const int j = v - p * PART_S;
    const float* src = partial + (size_t)(p * Bp) * PART_S + j;
    float g = 0.f;
    for (int b = 0; b < Bp; ++b) g += src[(size_t)b * PART_S];
    float t = dinv[v] * (g + u[v]);
    float h0 = fmaxf(fmaf(t, W[0], bb[0]), 0.f);
    float h1 = fmaxf(fmaf(t, W[1], bb[1]), 0.f);
    s[v] = h0 + h1;
}

// ================= fallback path (global atomics, proven) =================

__global__ __launch_bounds__(256) void k_init_deg(int* __restrict__ deg) {
    int i = blockIdx.x * 256 + threadIdx.x;
    if (i < N_NODES) deg[i] = 1;
}

__global__ __launch_bounds__(256) void k_deg(const int4* __restrict__ col4,
                                             int* __restrict__ deg) {
    int i = blockIdx.x * 256 + threadIdx.x;
    const int stride = gridDim.x * 256;
    const int n4 = N_EDGES / 4;
    for (; i < n4; i += stride) {
        int4 c = col4[i];
        atomicAdd(&deg[c.x], 1); atomicAdd(&deg[c.y], 1);
        atomicAdd(&deg[c.z], 1); atomicAdd(&deg[c.w], 1);
    }
}

__global__ __launch_bounds__(256) void k_dinv(const int* __restrict__ deg,
                                              const float* __restrict__ x,
                                              float* __restrict__ dinv,
                                              float* __restrict__ t) {
    int i = blockIdx.x * 256 + threadIdx.x;
    if (i >= N_NODES) return;
    float d = rsqrtf((float)deg[i]);
    dinv[i] = d;
    t[i] = d * d * x[i];
}

__global__ __launch_bounds__(256) void k_scatter(const int4* __restrict__ row4,
                                                 const int4* __restrict__ col4,
                                                 const float* __restrict__ x,
                                                 const float* __restrict__ dinv,
                                                 float* __restrict__ t) {
    int i = blockIdx.x * 256 + threadIdx.x;
    const int stride = gridDim.x * 256;
    const int n4 = N_EDGES / 4;
    for (; i < n4; i += stride) {
        int4 r = row4[i];
        int4 c = col4[i];
        atomicAdd(&t[c.x], dinv[r.x] * dinv[c.x] * x[r.x]);
        atomicAdd(&t[c.y], dinv[r.y] * dinv[c.y] * x[r.y]);
        atomicAdd(&t[c.z], dinv[r.z] * dinv[c.z] * x[r.z]);
        atomicAdd(&t[c.w], dinv[r.w] * dinv[c.w] * x[r.w]);
    }
}

__global__ __launch_bounds__(256) void k_node(const float* __restrict__ t,
                                              const float* __restrict__ W,
                                              const float* __restrict__ b,
                                              float* __restrict__ s) {
    int i = blockIdx.x * 256 + threadIdx.x;
    if (i >= N_NODES) return;
    float tv = t[i];
    float h0 = fmaxf(fmaf(tv, W[0], b[0]), 0.f);
    float h1 = fmaxf(fmaf(tv, W[1], b[1]), 0.f);
    s[i] = h0 + h1;
}

// ================= shared output kernel =================

__global__ __launch_bounds__(256) void k_out(const int4* __restrict__ rowA,
                                             const int4* __restrict__ colA,
                                             const int4* __restrict__ rowB,
                                             const int4* __restrict__ colB,
                                             const float* __restrict__ s,
                                             float4* __restrict__ out) {
    int i = blockIdx.x * 256 + threadIdx.x;
    const int stride = gridDim.x * 256;
    const int n4 = E_HALF / 4;
    for (; i < n4; i += stride) {
        int4 ra = rowA[i], ca = colA[i], rb = rowB[i], cb = colB[i];
        float y0 = s[ra.x] + s[ca.x] + s[rb.x] + s[cb.x];
        float y1 = s[ra.y] + s[ca.y] + s[rb.y] + s[cb.y];
        float y2 = s[ra.z] + s[ca.z] + s[rb.z] + s[cb.z];
        float y3 = s[ra.w] + s[ca.w] + s[rb.w] + s[cb.w];
        float4 o;
        o.x = 1.f / (1.f + __expf(-0.5f * y0));
        o.y = 1.f / (1.f + __expf(-0.5f * y1));
        o.z = 1.f / (1.f + __expf(-0.5f * y2));
        o.w = 1.f / (1.f + __expf(-0.5f * y3));
        out[i] = o;
    }
}

// ================= launch =================

extern "C" void kernel_launch(void* const* d_in, const int* in_sizes, int n_in,
                              void* d_out, int out_size, void* d_ws, size_t ws_size,
                              hipStream_t stream) {
    const float* x = (const float*)d_in[0];
    const float* W = (const float*)d_in[1];
    const float* b = (const float*)d_in[2];
    const int*   ei = (const int*)d_in[3];
    const int* row = ei;
    const int* col = ei + N_EDGES;
    float* out = (float*)d_out;

    char* ws = (char*)d_ws;
    float* dinv = (float*)(ws);                   // NP floats
    float* u    = (float*)(ws + (size_t)NP * 4);  // NP floats
    float* s    = (float*)(ws + (size_t)NP * 8);  // NP floats
    int*   deg  = (int*)  (ws + (size_t)NP * 12); // NP ints (fallback only)
    char*  partialBase = ws + (size_t)NP * 16;
    size_t avail = (ws_size > (size_t)NP * 16) ? ws_size - (size_t)NP * 16 : 0;

    // blocks-per-partition from available workspace
    // deg partial bytes  = NP_D * Bp_d * WORDS_D * 4 = Bp_d * 294912
    // scat partial bytes = NP_S * Bp_s * PART_S * 4 = Bp_s * 589824
    int Bp_d = (int)(avail / 294912);
    if (Bp_d > 128) Bp_d = 128;
    int Bp_s = (int)(avail / 589824);
    if (Bp_s > 64) Bp_s = 64;

    const int nodeBlocks = (N_NODES + 255) / 256;
    const int edgeBlocks = 2048;

    if (Bp_s >= 2 && Bp_d >= 2) {
        unsigned* partU = (unsigned*)partialBase;
        float*    partF = (float*)partialBase;  // reused after reduceA consumed partU
        k_deg_part<<<NP_D * Bp_d, 1024, 0, stream>>>((const int4*)col, partU, Bp_d);
        k_reduceA<<<nodeBlocks, 256, 0, stream>>>(partU, x, Bp_d, dinv, u);
        k_scat_part<<<NP_S * Bp_s, 1024, 0, stream>>>((const int4*)row, (const int4*)col,
                                                      u, partF, Bp_s);
        k_reduceB<<<nodeBlocks, 256, 0, stream>>>(partF, dinv, u, W, b, Bp_s, s);
    } else {
        // fallback: global-atomic path
        k_init_deg<<<nodeBlocks, 256, 0, stream>>>(deg);
        k_deg<<<edgeBlocks, 256, 0, stream>>>((const int4*)col, deg);
        k_dinv<<<nodeBlocks, 256, 0, stream>>>(deg, x, dinv, u);
        k_scatter<<<edgeBlocks, 256, 0, stream>>>((const int4*)row, (const int4*)col,
                                                  x, dinv, u);
        k_node<<<nodeBlocks, 256, 0, stream>>>(u, W, b, s);
    }

    k_out<<<edgeBlocks, 256, 0, stream>>>((const int4*)row, (const int4*)col,
                                          (const int4*)(row + E_HALF),
                                          (const int4*)(col + E_HALF),
                                          s, (float4*)out);
}